// Round 1
// baseline (346.850 us; speedup 1.0000x reference)
//
#include <hip/hip_runtime.h>

#define N_STEPS 50
#define DT 0.01f

// One thread per batch element. State in registers; actions buffered in
// register float4 chunks (aligned: b*100 floats = b*400 bytes, multiple of 16).
// Output written as 2x float4 per step (contiguous per thread).
__global__ __launch_bounds__(256) void hybrid_sim_kernel(
    const float* __restrict__ fs,
    const float* __restrict__ actions,
    const float* __restrict__ pm,  const float* __restrict__ pCaf,
    const float* __restrict__ pCar, const float* __restrict__ plf,
    const float* __restrict__ plr, const float* __restrict__ pIz,
    float* __restrict__ out, int batch)
{
    int b = blockIdx.x * blockDim.x + threadIdx.x;
    if (b >= batch) return;

    // full_states[b, 0, 0:8]
    const float4* fsp = (const float4*)(fs + (size_t)b * 8);
    float4 f0 = fsp[0];
    float4 f1 = fsp[1];
    float s0 = f0.x, s1 = f0.y, s2 = f0.z, s3 = f0.w;
    float s4 = f1.x, s5 = f1.y, u0 = f1.z, u1 = f1.w;

    // Wave-uniform coefficients (scalar inputs)
    float m  = *pm,  Caf = *pCaf, Car = *pCar;
    float lf = *plf, lr  = *plr,  Iz  = *pIz;
    float k1  = 2.f * (Caf + Car) / m;            // -(2Caf+2Car)/(m Vx) = -k1/Vx
    float k2  = 2.f * (Caf * lf - Car * lr) / m;  // A35 = -Vx - k2/Vx
    float k3  = 2.f * (lf * Caf - lr * Car) / Iz; // A53 = -k3/Vx
    float k4  = 2.f * (lf * lf * Caf + lr * lr * Car) / Iz; // A54 = -k4/Vx
    float b31 = 2.f * Caf / m;
    float b51 = 2.f * lf * Caf / Iz;

    const float4* ap = (const float4*)(actions + (size_t)b * 100);
    float4*       op = (float4*)(out + (size_t)b * 400);

    for (int chunk = 0; chunk < 5; ++chunk) {
        float4 abuf[5];
        #pragma unroll
        for (int j = 0; j < 5; ++j) abuf[j] = ap[chunk * 5 + j];
        const float* av = (const float*)abuf;

        #pragma unroll
        for (int tt = 0; tt < 10; ++tt) {
            float psi = s4;
            float c  = __cosf(psi);
            float sn = __sinf(psi);
            // body-frame: only sb1 (=Vx) and sb3 are consumed downstream
            float Vx  = c * s1 + sn * s3;
            float sb3 = c * s3 - sn * s1;
            float inv = __builtin_amdgcn_rcpf(Vx);
            // temp vector (temp0=Vx, temp1=u0, temp2=sb3, temp4=s5)
            float t3 = -k1 * inv * sb3 + (-Vx - k2 * inv) * s5 + b31 * u1;
            float t5 = -k3 * inv * sb3 - k4 * inv * psi + b51 * u1;
            // pred = s + R(psi) * temp * dt
            float p0 = s0 + DT * (c * Vx - sn * sb3);
            float p2 = s2 + DT * (sn * Vx + c * sb3);
            float p1 = s1 + DT * (c * u0 - sn * t3);
            float p3 = s3 + DT * (sn * u0 + c * t3);
            float p4 = s4 + DT * s5;
            float p5 = s5 + DT * t5;

            float nu0 = av[2 * tt];
            float nu1 = av[2 * tt + 1];

            int t = chunk * 10 + tt;
            float4 o0; o0.x = p0; o0.y = p1; o0.z = p2; o0.w = p3;
            float4 o1; o1.x = p4; o1.y = p5; o1.z = nu0; o1.w = nu1;
            op[2 * t]     = o0;
            op[2 * t + 1] = o1;

            s0 = p0; s1 = p1; s2 = p2; s3 = p3; s4 = p4; s5 = p5;
            u0 = nu0; u1 = nu1;
        }
    }
}

extern "C" void kernel_launch(void* const* d_in, const int* in_sizes, int n_in,
                              void* d_out, int out_size, void* d_ws, size_t ws_size,
                              hipStream_t stream) {
    const float* fs      = (const float*)d_in[0]; // (B,1,8)
    const float* actions = (const float*)d_in[1]; // (B,50,2)
    int batch = in_sizes[0] / 8;
    int block = 256;
    int grid  = (batch + block - 1) / block;
    hybrid_sim_kernel<<<grid, block, 0, stream>>>(
        fs, actions,
        (const float*)d_in[2], (const float*)d_in[3], (const float*)d_in[4],
        (const float*)d_in[5], (const float*)d_in[6], (const float*)d_in[7],
        (float*)d_out, batch);
}

// Round 2
// 318.139 us; speedup vs baseline: 1.0902x; 1.0902x over previous
//
#include <hip/hip_runtime.h>

#define DT 0.01f
#define ROW 18   // dwords per element-row in LDS stage: 16 data + 2 pad (conflict-free for b64)

// Each thread simulates one batch element (sequential 50-step scan in registers).
// Output path: groups of 2 steps (= 16 dwords = one 64B sector per element) are
// staged in per-wave LDS, then drained with fully sector-coalesced float2 stores
// (8 lanes cover each 64B sector). Double-buffered, 1 barrier per group.
__global__ __launch_bounds__(256) void hybrid_sim_kernel(
    const float* __restrict__ fs,
    const float* __restrict__ actions,
    const float* __restrict__ pm,  const float* __restrict__ pCaf,
    const float* __restrict__ pCar, const float* __restrict__ plf,
    const float* __restrict__ plr, const float* __restrict__ pIz,
    float* __restrict__ out)
{
    __shared__ float lds[2 * 4 * 64 * ROW];   // 36864 B -> 4 blocks/CU

    const int tid  = threadIdx.x;
    const int lane = tid & 63;
    const int wv   = tid >> 6;
    const int b    = blockIdx.x * 256 + tid;          // this thread's batch elem
    const int b0w  = blockIdx.x * 256 + (wv << 6);    // wave's first batch elem

    // initial state: full_states[b, 0, 0:8]
    const float4* fsp = (const float4*)(fs + (size_t)b * 8);
    float4 f0 = fsp[0];
    float4 f1 = fsp[1];
    float s0=f0.x, s1=f0.y, s2=f0.z, s3=f0.w, s4=f1.x, s5=f1.y, u0=f1.z, u1=f1.w;

    // wave-uniform coefficients
    float m=*pm, Caf=*pCaf, Car=*pCar, lf=*plf, lr=*plr, Iz=*pIz;
    float k1  = 2.f*(Caf+Car)/m;
    float k2  = 2.f*(Caf*lf-Car*lr)/m;
    float k3  = 2.f*(lf*Caf-lr*Car)/Iz;
    float k4  = 2.f*(lf*lf*Caf+lr*lr*Car)/Iz;
    float b31 = 2.f*Caf/m;
    float b51 = 2.f*lf*Caf/Iz;

    const float4* ap = (const float4*)(actions + (size_t)b * 100);

    float* base0 = &lds[(0*4 + wv) * 64 * ROW];
    float* base1 = &lds[(1*4 + wv) * 64 * ROW];

    float o[16];

    for (int chunk = 0; chunk < 5; ++chunk) {
        float4 abuf[5];
        #pragma unroll
        for (int j = 0; j < 5; ++j) abuf[j] = ap[chunk*5 + j];
        const float* av = (const float*)abuf;

        #pragma unroll
        for (int gg = 0; gg < 5; ++gg) {        // 5 groups of 2 steps per chunk
            #pragma unroll
            for (int hh = 0; hh < 2; ++hh) {
                int tt = gg*2 + hh;             // step within chunk
                float psi = s4;
                float c  = __cosf(psi);
                float sn = __sinf(psi);
                float Vx  = c*s1 + sn*s3;
                float sb3 = c*s3 - sn*s1;
                float inv = __builtin_amdgcn_rcpf(Vx);
                float t3 = -k1*inv*sb3 + (-Vx - k2*inv)*s5 + b31*u1;
                float t5 = -k3*inv*sb3 - k4*inv*psi + b51*u1;
                float p0 = s0 + DT*(c*Vx - sn*sb3);
                float p2 = s2 + DT*(sn*Vx + c*sb3);
                float p1 = s1 + DT*(c*u0 - sn*t3);
                float p3 = s3 + DT*(sn*u0 + c*t3);
                float p4 = s4 + DT*s5;
                float p5 = s5 + DT*t5;
                float nu0 = av[2*tt];
                float nu1 = av[2*tt+1];
                float* oo = &o[hh*8];
                oo[0]=p0; oo[1]=p1; oo[2]=p2; oo[3]=p3;
                oo[4]=p4; oo[5]=p5; oo[6]=nu0; oo[7]=nu1;
                s0=p0; s1=p1; s2=p2; s3=p3; s4=p4; s5=p5; u0=nu0; u1=nu1;
            }

            int g = chunk*5 + gg;               // global group index 0..24
            float* buf = (g & 1) ? base1 : base0;

            // stage: 8 x ds_write_b64, bank-uniform (row stride 18 dwords)
            float2* rw = (float2*)(buf + lane*ROW);
            #pragma unroll
            for (int j = 0; j < 8; ++j) rw[j] = make_float2(o[2*j], o[2*j+1]);

            __syncthreads();

            // drain: 8 store instrs, each covers 8 full 64B sectors (8 lanes/sector)
            #pragma unroll
            for (int k = 0; k < 8; ++k) {
                int e  = k*8 + (lane >> 3);     // element within wave
                int mm = lane & 7;              // float2 slot within sector
                float2 v = *(const float2*)(buf + e*ROW + mm*2);
                float2* dst = (float2*)(out + (size_t)(b0w + e)*400 + g*16 + mm*2);
                *dst = v;
            }
        }
    }
}

extern "C" void kernel_launch(void* const* d_in, const int* in_sizes, int n_in,
                              void* d_out, int out_size, void* d_ws, size_t ws_size,
                              hipStream_t stream) {
    const float* fs      = (const float*)d_in[0]; // (B,1,8)
    const float* actions = (const float*)d_in[1]; // (B,50,2)
    int batch = in_sizes[0] / 8;                  // 131072, divisible by 256
    int grid  = batch / 256;
    hybrid_sim_kernel<<<grid, 256, 0, stream>>>(
        fs, actions,
        (const float*)d_in[2], (const float*)d_in[3], (const float*)d_in[4],
        (const float*)d_in[5], (const float*)d_in[6], (const float*)d_in[7],
        (float*)d_out);
}

// Round 3
// 303.170 us; speedup vs baseline: 1.1441x; 1.0494x over previous
//
#include <hip/hip_runtime.h>

#define DT 0.01f
#define ROW 18   // dwords per element-row in LDS stage: 16 data + 2 pad (2-way = free)

// One thread per batch element; 50-step sequential scan in registers.
// All 400 B of per-thread actions preloaded into registers up front (wave's
// 25.6 KB footprint is L1-resident during the load burst -> each HBM sector
// fetched once). Output staged per-wave in private LDS (NO barriers needed --
// intra-wave lgkmcnt ordering suffices), drained as sector-coalesced float2
// stores (8 full 64B sectors per store instruction).
__global__ __launch_bounds__(256) void hybrid_sim_kernel(
    const float* __restrict__ fs,
    const float* __restrict__ actions,
    const float* __restrict__ pm,  const float* __restrict__ pCaf,
    const float* __restrict__ pCar, const float* __restrict__ plf,
    const float* __restrict__ plr, const float* __restrict__ pIz,
    float* __restrict__ out)
{
    __shared__ float lds[4 * 64 * ROW];   // 18.4 KB, wave-private quarters

    const int tid  = threadIdx.x;
    const int lane = tid & 63;
    const int wv   = tid >> 6;
    const int b    = blockIdx.x * 256 + tid;
    const int b0w  = blockIdx.x * 256 + (wv << 6);

    // initial state: full_states[b, 0, 0:8]
    const float4* fsp = (const float4*)(fs + (size_t)b * 8);
    float4 f0 = fsp[0];
    float4 f1 = fsp[1];
    float s0=f0.x, s1=f0.y, s2=f0.z, s3=f0.w, s4=f1.x, s5=f1.y, u0=f1.z, u1=f1.w;

    // wave-uniform coefficients
    float m=*pm, Caf=*pCaf, Car=*pCar, lf=*plf, lr=*plr, Iz=*pIz;
    float k1  = 2.f*(Caf+Car)/m;
    float k2  = 2.f*(Caf*lf-Car*lr)/m;
    float k3  = 2.f*(lf*Caf-lr*Car)/Iz;
    float k4  = 2.f*(lf*lf*Caf+lr*lr*Car)/Iz;
    float b31 = 2.f*Caf/m;
    float b51 = 2.f*lf*Caf/Iz;

    // preload ALL actions for this thread: 25 float4 = 400 B
    const float4* ap = (const float4*)(actions + (size_t)b * 100);
    float4 abuf[25];
    #pragma unroll
    for (int j = 0; j < 25; ++j) abuf[j] = ap[j];
    const float* av = (const float*)abuf;

    float* buf = &lds[wv * 64 * ROW];
    float o[16];

    #pragma unroll
    for (int g = 0; g < 25; ++g) {          // 25 groups of 2 steps
        #pragma unroll
        for (int hh = 0; hh < 2; ++hh) {
            int tt = g*2 + hh;              // global step index
            float psi = s4;
            float c  = __cosf(psi);
            float sn = __sinf(psi);
            float Vx  = c*s1 + sn*s3;
            float sb3 = c*s3 - sn*s1;
            float inv = __builtin_amdgcn_rcpf(Vx);
            float t3 = -k1*inv*sb3 + (-Vx - k2*inv)*s5 + b31*u1;
            float t5 = -k3*inv*sb3 - k4*inv*psi + b51*u1;
            float p0 = s0 + DT*(c*Vx - sn*sb3);
            float p2 = s2 + DT*(sn*Vx + c*sb3);
            float p1 = s1 + DT*(c*u0 - sn*t3);
            float p3 = s3 + DT*(sn*u0 + c*t3);
            float p4 = s4 + DT*s5;
            float p5 = s5 + DT*t5;
            float nu0 = av[2*tt];
            float nu1 = av[2*tt+1];
            float* oo = &o[hh*8];
            oo[0]=p0; oo[1]=p1; oo[2]=p2; oo[3]=p3;
            oo[4]=p4; oo[5]=p5; oo[6]=nu0; oo[7]=nu1;
            s0=p0; s1=p1; s2=p2; s3=p3; s4=p4; s5=p5; u0=nu0; u1=nu1;
        }

        // stage: 8 x ds_write_b64 into wave-private LDS (no barrier needed)
        float2* rw = (float2*)(buf + lane*ROW);
        #pragma unroll
        for (int j = 0; j < 8; ++j) rw[j] = make_float2(o[2*j], o[2*j+1]);

        // drain: 8 store instrs, each covering 8 full 64B sectors
        #pragma unroll
        for (int k = 0; k < 8; ++k) {
            int e  = k*8 + (lane >> 3);     // element within wave
            int mm = lane & 7;              // float2 slot within sector
            float2 v = *(const float2*)(buf + e*ROW + mm*2);
            float2* dst = (float2*)(out + (size_t)(b0w + e)*400 + g*16 + mm*2);
            *dst = v;
        }
    }
}

extern "C" void kernel_launch(void* const* d_in, const int* in_sizes, int n_in,
                              void* d_out, int out_size, void* d_ws, size_t ws_size,
                              hipStream_t stream) {
    const float* fs      = (const float*)d_in[0]; // (B,1,8)
    const float* actions = (const float*)d_in[1]; // (B,50,2)
    int batch = in_sizes[0] / 8;                  // 131072, divisible by 256
    int grid  = batch / 256;
    hybrid_sim_kernel<<<grid, 256, 0, stream>>>(
        fs, actions,
        (const float*)d_in[2], (const float*)d_in[3], (const float*)d_in[4],
        (const float*)d_in[5], (const float*)d_in[6], (const float*)d_in[7],
        (float*)d_out);
}